// Round 11
// baseline (575.130 us; speedup 1.0000x reference)
//
#include <hip/hip_runtime.h>

// Problem constants: N=512, BS=64, DIM=256, SIZE=8192
#define T_TOTAL 32768   // N*BS queries
#define D       256
#define K       8192
#define BQ      64      // queries per block tile (2 row-tiles of 32) — shared by all 8 waves
#define KSPLIT  4
#define KSLICE  (K / KSPLIT)
#define NSLICE  (KSPLIT * 4)        // (slice, wn<4) pairs write disjoint partial slices
#define NCT32   256                 // 32-code tiles
#define KT16    131072              // halves per 16-dim slab plane (NCT32*64*8)
#define NQB     (T_TOTAL / BQ)      // 512 query-blocks

typedef _Float16 half4f   __attribute__((ext_vector_type(4)));
typedef _Float16 half8f   __attribute__((ext_vector_type(8)));
typedef float    floatx16 __attribute__((ext_vector_type(16)));

// d_out scratch: Bhi/Blo after the first PARTIAL_F floats.
#define PARTIAL_F 1048576
#define BHALVES   2097152   // halves per B array (16 slabs * 131072) — same footprint

__device__ __forceinline__ _Float16 hi16(float x) { return (_Float16)x; }
__device__ __forceinline__ _Float16 lo16(float x, _Float16 h) { return (_Float16)(x - (float)h); }
__device__ __forceinline__ void split4(float4 v, half4f& h, half4f& l) {
    _Float16 hx = hi16(v.x), hy = hi16(v.y), hz = hi16(v.z), hw = hi16(v.w);
    h = (half4f){hx, hy, hz, hw};
    l = (half4f){lo16(v.x, hx), lo16(v.y, hy), lo16(v.z, hz), lo16(v.w, hw)};
}

// ---- kernel 1: vocab prep, NEGATED, in mfma_32x32x16_f16 B-fragment order ----
// 256 blocks, one 32-code tile each; wave w handles codes 8w..8w+7 (lane = k4 along D).
// Layout (R1 harness-verified): per 16-dim slab kt, lane = col + 32*(k>>3), elem = k&7.
__global__ void prep_kernel(const float* __restrict__ vocab,
                            _Float16* __restrict__ bhi, _Float16* __restrict__ blo,
                            float* __restrict__ hv2) {
    const int ct = blockIdx.x;           // 32-code tile 0..255
    const int t  = threadIdx.x;
    const int k4 = t & 63;               // float4 index along D
    const int w  = t >> 6;
    const float4* voc4 = (const float4*)vocab;
    const int kt = k4 >> 2;              // 16-dim slab (4 float4 per slab)
    const int q  = k4 & 3;
    const int fl = 32 * (q >> 1);        // lane high-half from k-octet
    const int i0 = (q & 1) * 4;
    float ss[8];
    #pragma unroll
    for (int ci = 0; ci < 8; ++ci) {
        int cc = w * 8 + ci;             // code within tile
        float4 v = voc4[(size_t)(ct * 32 + cc) * (D / 4) + k4];
        ss[ci] = v.x * v.x + v.y * v.y + v.z * v.z + v.w * v.w;
        float4 nv = make_float4(-v.x, -v.y, -v.z, -v.w);
        half4f hh, ll;
        split4(nv, hh, ll);
        size_t off = (((size_t)kt * NCT32 + ct) * 64 + (cc + fl)) * 8 + i0;
        *(half4f*)&bhi[off] = hh;
        *(half4f*)&blo[off] = ll;
    }
    #pragma unroll
    for (int ci = 0; ci < 8; ++ci) {
        float s = ss[ci];
        #pragma unroll
        for (int off = 32; off; off >>= 1) s += __shfl_down(s, off, 64);
        if ((t & 63) == 0) hv2[ct * 32 + w * 8 + ci] = 0.5f * s;
    }
}

// -- kernel 2: MFMA argmin; 3-term split; 32x32x16 shape on the R10 diet structure --
// Model (R0-R10): dur ~= MFMA_pipe + VALU_pipe - small overlap. R10 cut VALU (win,
// -21us, 1:1 with prediction); MFMA floor is 215us at 16x16 (1955 TF). 32x32x16 runs
// at 2178 TF -> floor 193us AND halves MFMA instruction count. R1 verified all 32x32
// fragment layouts end-to-end (absmax 0); its regression was the schedule (since
// rebuilt), not the shape. Keep: 8 code-split waves, no prefetch, walking pointers,
// negated-B + hv-init acc, packed bidx. Loop = kt-PAIR (two 16-dim slabs): burst =
// 12 MFMA (~443cy) preserving R10's load/burst rhythm. Risk: 2 acc chains (dependent
// MFMAs 2 issues apart) — if MfmaUtil drops <55, that's the stall signature -> 4-chain.
__launch_bounds__(512, 2)
__global__ void argmin_kernel(const float* __restrict__ seq,
                              const _Float16* __restrict__ bhi,
                              const _Float16* __restrict__ blo,
                              const float* __restrict__ hv2,
                              float2* __restrict__ partial) {
    // A LDS in fragment order [mi 0..1][slab 0..15][flane 0..63][8], XOR-swizzle slab<<3
    __shared__ _Float16 AhL[2 * 16 * 64 * 8];   // 32 KB
    __shared__ _Float16 AlL[2 * 16 * 64 * 8];   // 32 KB

    const int t    = threadIdx.x;
    const int lane = t & 63;
    const int wn   = t >> 6;            // code octant 0..7 (one 32-code tile per c0)
    const int bi   = blockIdx.x;
    const int slice = (bi & 7) >> 1;    // 0..3  (XCD-locked K-slice)
    const int qb    = (bi >> 3) * 2 + (bi & 1);  // 0..511
    const int q0   = qb * BQ;
    const int k0   = slice * KSLICE;

    const float4* seq4 = (const float4*)seq;

    // ---- prologue: split A (64 rows x 256 dims) into fragment-order LDS, once ----
    #pragma unroll
    for (int i = 0; i < 8; ++i) {
        int f   = t + 512 * i;          // 0..4095 float4s
        int row = f >> 6;               // 0..63
        int d4  = f & 63;               // float4 along D
        float4 v = seq4[(size_t)(q0 + row) * (D / 4) + d4];
        half4f h, l;
        split4(v, h, l);
        int kt = d4 >> 2, q = d4 & 3;
        int off = (((((row >> 5) * 16 + kt) * 64) + ((row & 31) + 32 * (q >> 1))) * 8
                   + (q & 1) * 4)
                  ^ (kt << 3);          // swizzle: write conflicts 32-way -> ~4-way
        *(half4f*)&AhL[off] = h;
        *(half4f*)&AlL[off] = l;
    }
    __syncthreads();

    float    best[32];
    unsigned bidxp[16];                 // 2x16-bit packed indices (K fits in 13 bits)
    #pragma unroll
    for (int b = 0; b < 32; ++b) best[b] = 3.4e38f;
    #pragma unroll
    for (int b = 0; b < 16; ++b) bidxp[b] = 0u;

    const int lane8  = lane << 3;
    const int cidx   = lane & 31;

    // walking B pointers: tile base = ((k0>>5) + wn) * 512 halves
    const size_t cb0 = ((size_t)(k0 >> 5) + wn) * 512;
    const _Float16* pbh = bhi + cb0 + lane8;
    const _Float16* pbl = blo + cb0 + lane8;

    // hv for tile 0; subsequent tiles prefetched pre-epilogue
    float hvn = hv2[k0 + wn * 32 + cidx];

    for (int c0i = 0; c0i < KSLICE / 256; ++c0i) {   // 8 c0 tiles of 256 codes
        const int c0 = k0 + c0i * 256;

        // acc init: chain 0 carries 0.5|v|^2 (negated B -> acc accumulates the score)
        floatx16 acc[2];
        #pragma unroll
        for (int r = 0; r < 16; ++r) { acc[0][r] = hvn; acc[1][r] = hvn; }
        // NOTE: acc[mi] both start at hvn? NO — each acc[mi] is a full score for rows
        // mi*32..mi*32+31; both need the hv init (hv depends only on code col). OK.

        #pragma unroll 1   // REAL loop: bounded hoist window (anti-spill)
        for (int j = 0; j < 8; ++j) {   // kt-pair: slabs 2j, 2j+1
            // B: 4x16B loads off 2 walking pointers (+KT16 computed, then advance)
            half8f bh0 = *(const half8f*)pbh;
            half8f bl0 = *(const half8f*)pbl;
            half8f bh1 = *(const half8f*)(pbh + KT16);
            half8f bl1 = *(const half8f*)(pbl + KT16);
            pbh += 2 * (size_t)KT16;
            pbl += 2 * (size_t)KT16;
            // A: per slab one XOR+add; mi-term (8192 halves = 16KB) folds in ds imm
            const int ak0 = ((2 * j) << 9) + (lane8 ^ ((2 * j) << 3));
            const int ak1 = ((2 * j + 1) << 9) + (lane8 ^ ((2 * j + 1) << 3));
            half8f al0[2], ah0[2], al1[2], ah1[2];
            #pragma unroll
            for (int mi = 0; mi < 2; ++mi) {
                al0[mi] = *(const half8f*)&AlL[ak0 + mi * 8192];
                ah0[mi] = *(const half8f*)&AhL[ak0 + mi * 8192];
                al1[mi] = *(const half8f*)&AlL[ak1 + mi * 8192];
                ah1[mi] = *(const half8f*)&AhL[ak1 + mi * 8192];
            }
            // 12 MFMAs, term-outer, (slab,mi)-interleaved: same-acc pairs 2 apart
            __builtin_amdgcn_s_setprio(1);
            acc[0] = __builtin_amdgcn_mfma_f32_32x32x16_f16(al0[0], bh0, acc[0], 0, 0, 0);
            acc[1] = __builtin_amdgcn_mfma_f32_32x32x16_f16(al0[1], bh0, acc[1], 0, 0, 0);
            acc[0] = __builtin_amdgcn_mfma_f32_32x32x16_f16(al1[0], bh1, acc[0], 0, 0, 0);
            acc[1] = __builtin_amdgcn_mfma_f32_32x32x16_f16(al1[1], bh1, acc[1], 0, 0, 0);
            acc[0] = __builtin_amdgcn_mfma_f32_32x32x16_f16(ah0[0], bl0, acc[0], 0, 0, 0);
            acc[1] = __builtin_amdgcn_mfma_f32_32x32x16_f16(ah0[1], bl0, acc[1], 0, 0, 0);
            acc[0] = __builtin_amdgcn_mfma_f32_32x32x16_f16(ah1[0], bl1, acc[0], 0, 0, 0);
            acc[1] = __builtin_amdgcn_mfma_f32_32x32x16_f16(ah1[1], bl1, acc[1], 0, 0, 0);
            acc[0] = __builtin_amdgcn_mfma_f32_32x32x16_f16(ah0[0], bh0, acc[0], 0, 0, 0);
            acc[1] = __builtin_amdgcn_mfma_f32_32x32x16_f16(ah0[1], bh0, acc[1], 0, 0, 0);
            acc[0] = __builtin_amdgcn_mfma_f32_32x32x16_f16(ah1[0], bh1, acc[0], 0, 0, 0);
            acc[1] = __builtin_amdgcn_mfma_f32_32x32x16_f16(ah1[1], bh1, acc[1], 0, 0, 0);
            __builtin_amdgcn_s_setprio(0);
        }
        // rewind to next c0 tile: consumed 16 slabs (16*KT16), tile stride 8*512
        pbh += 4096 - 16 * (size_t)KT16;
        pbl += 4096 - 16 * (size_t)KT16;

        // prefetch next tile's hv BEFORE the epilogue (epilogue hides the latency)
        float hvn_nx = hvn;
        if (c0i < KSLICE / 256 - 1) hvn_nx = hv2[c0 + 256 + wn * 32 + cidx];

        // epilogue: acc IS the score; running first-argmin (ascending c per lane).
        // C/D 32x32 (R1-verified): col = lane&31, row = (r&3)+8*(r>>2)+4*(lane>>5)
        {
            const int c = c0 + wn * 32 + cidx;
            const unsigned clo = (unsigned)c;
            const unsigned chi = (unsigned)c << 16;
            #pragma unroll
            for (int mi = 0; mi < 2; ++mi)
                #pragma unroll
                for (int r = 0; r < 16; r += 2) {
                    const int b = mi * 16 + r;
                    float s0 = acc[mi][r];
                    float s1 = acc[mi][r + 1];
                    unsigned w = bidxp[b >> 1];
                    if (s0 < best[b])     { best[b] = s0;     w = (w & 0xFFFF0000u) | clo; }
                    if (s1 < best[b + 1]) { best[b + 1] = s1; w = (w & 0x0000FFFFu) | chi; }
                    bidxp[b >> 1] = w;
                }
        }
        hvn = hvn_nx;
    }

    // unpack indices (registers are cheap after the hot loop)
    int bidx[32];
    #pragma unroll
    for (int b = 0; b < 32; ++b)
        bidx[b] = (b & 1) ? (int)(bidxp[b >> 1] >> 16) : (int)(bidxp[b >> 1] & 0xFFFFu);

    // reduce across the 32 col-lanes (xor<32 keeps lane>>5, the row-half bit)
    #pragma unroll
    for (int off = 1; off < 32; off <<= 1) {
        #pragma unroll
        for (int b = 0; b < 32; ++b) {
            float ob = __shfl_xor(best[b], off, 64);
            int   oi = __shfl_xor(bidx[b], off, 64);
            if (ob < best[b] || (ob == best[b] && oi < bidx[b])) {
                best[b] = ob; bidx[b] = oi;
            }
        }
    }

    // fold waves wn>=4 into wn<4 via (now dead) A-LDS, keeping NSLICE=16.
    // 2 writer lanes per wave (lane 0: row-half hi=0, lane 32: hi=1), 32 rows each.
    float2* fold = (float2*)AhL;        // 4 waves x 64 rows x float2 = 2 KB
    const int hi4 = (lane >> 5) * 4;
    __syncthreads();                    // everyone done reading A
    if (wn >= 4 && (lane & 31) == 0) {
        #pragma unroll
        for (int mi = 0; mi < 2; ++mi)
            #pragma unroll
            for (int r = 0; r < 16; ++r) {
                int row = mi * 32 + (r & 3) + 8 * (r >> 2) + hi4;
                fold[(wn - 4) * 64 + row] =
                    make_float2(best[mi * 16 + r], (float)bidx[mi * 16 + r]);
            }
    }
    __syncthreads();
    if (wn < 4 && (lane & 31) == 0) {
        const size_t sl = (size_t)(slice * 4 + wn) * T_TOTAL;  // disjoint per (slice, wn)
        #pragma unroll
        for (int mi = 0; mi < 2; ++mi)
            #pragma unroll
            for (int r = 0; r < 16; ++r) {
                int row = mi * 32 + (r & 3) + 8 * (r >> 2) + hi4;
                int b = mi * 16 + r;
                float2 p = fold[wn * 64 + row];
                int pi = (int)p.y;
                if (p.x < best[b] || (p.x == best[b] && pi < bidx[b])) {
                    best[b] = p.x; bidx[b] = pi;
                }
                partial[sl + q0 + row] = make_float2(best[b], (float)bidx[b]);
            }
    }
}

// ---- kernel 3a (fused, needs partial in ws): fold 16 slices + gather, wave per row ----
__global__ void redgather_kernel(const float* __restrict__ vocab,
                                 const float2* __restrict__ partial,
                                 float* __restrict__ out) {
    int r    = blockIdx.x * 4 + (threadIdx.x >> 6);
    int lane = threadIdx.x & 63;
    float bm = 3.4e38f;
    int   bi = 0x7fffffff;
    if (lane < 16) {
        float2 p = partial[(size_t)lane * T_TOTAL + r];
        bm = p.x; bi = (int)p.y;
    }
    #pragma unroll
    for (int off = 1; off < 16; off <<= 1) {   // xor<16 stays within the 16-lane group
        float ob = __shfl_xor(bm, off, 64);
        int   oi = __shfl_xor(bi, off, 64);
        if (ob < bm || (ob == bm && oi < bi)) { bm = ob; bi = oi; }
    }
    int k = __shfl(bi, 0, 64);                 // lanes 0-15 hold the true min; take lane 0
    const float4* src = (const float4*)(vocab + (size_t)k * D);
    float4*       dst = (float4*)(out + (size_t)r * D);
    dst[lane] = src[lane];
    if (lane == 0) out[(size_t)T_TOTAL * D + r] = (float)k;
}

// ---- kernel 3b/4b (fallback path, partial at d_out head): separate reduce + gather ----
__global__ void reduce_kernel(const float2* __restrict__ partial, int* __restrict__ idx) {
    int q = blockIdx.x * 256 + threadIdx.x;
    float bm = 3.4e38f;
    int   bi = 0x7fffffff;
    #pragma unroll
    for (int s = 0; s < NSLICE; ++s) {
        float2 p = partial[(size_t)s * T_TOTAL + q];
        int pi = (int)p.y;
        if (p.x < bm || (p.x == bm && pi < bi)) { bm = p.x; bi = pi; }
    }
    idx[q] = bi;
}

__global__ void gather_kernel(const float* __restrict__ vocab,
                              const int* __restrict__ idx,
                              float* __restrict__ out) {
    int r    = blockIdx.x * 4 + (threadIdx.x >> 6);
    int lane = threadIdx.x & 63;
    int k = idx[r];
    const float4* src = (const float4*)(vocab + (size_t)k * D);
    float4*       dst = (float4*)(out + (size_t)r * D);
    dst[lane] = src[lane];
    if (lane == 0) out[(size_t)T_TOTAL * D + r] = (float)k;
}

extern "C" void kernel_launch(void* const* d_in, const int* in_sizes, int n_in,
                              void* d_out, int out_size, void* d_ws, size_t ws_size,
                              hipStream_t stream) {
    const float* seq   = (const float*)d_in[0];   // [T, D] f32
    const float* vocab = (const float*)d_in[1];   // [K, D] f32
    float* out = (float*)d_out;

    float* hv2 = (float*)d_ws;                               // K floats
    _Float16* bhi = (_Float16*)(out + PARTIAL_F);            // 4 MB (d_out scratch)
    _Float16* blo = bhi + BHALVES;                           // 4 MB

    // partial placement: ws if it fits (enables fused reduce+gather — no cross-kernel
    // race since gather never writes ws), else d_out head (R12 2-kernel path).
    const size_t need_ws = (size_t)(K + 2 * NSLICE * T_TOTAL) * sizeof(float) + 256;
    const bool fused = ws_size >= need_ws;

    hipLaunchKernelGGL(prep_kernel, dim3(NCT32), dim3(256), 0, stream, vocab, bhi, blo, hv2);

    if (fused) {
        float2* partial = (float2*)(hv2 + K);                // in ws
        hipLaunchKernelGGL(argmin_kernel,    dim3(NQB * KSPLIT), dim3(512), 0, stream,
                           seq, bhi, blo, hv2, partial);
        hipLaunchKernelGGL(redgather_kernel, dim3(T_TOTAL / 4),  dim3(256), 0, stream,
                           vocab, partial, out);
    } else {
        float2* partial = (float2*)d_out;                    // at d_out head
        int* idx = (int*)(hv2 + K);                          // T ints in ws
        hipLaunchKernelGGL(argmin_kernel, dim3(NQB * KSPLIT), dim3(512), 0, stream,
                           seq, bhi, blo, hv2, partial);
        hipLaunchKernelGGL(reduce_kernel, dim3(T_TOTAL / 256), dim3(256), 0, stream, partial, idx);
        hipLaunchKernelGGL(gather_kernel, dim3(T_TOTAL / 4),   dim3(256), 0, stream, vocab, idx, out);
    }
}